// Round 5
// baseline (365.356 us; speedup 1.0000x reference)
//
#include <hip/hip_runtime.h>
#include <math.h>

#define NMODES 32
#define NPAIR 496
#define TAYLOR_N 12

// T2 matrix in module-scope device memory (d_ws may be zero-sized).
__device__ float2 g_T2[NMODES * NMODES];

// Wave-internal LDS sync: block == 1 wave, so no s_barrier needed and no
// vmcnt(0) drain of trajectory stores. LDS ops complete in order per wave;
// lgkmcnt(0) makes prior ds_writes visible to subsequent ds_reads.
#define WSYNC() __asm__ volatile("s_waitcnt lgkmcnt(0)" ::: "memory")

__device__ __forceinline__ void cfma(float2& acc, float2 a, float bre, float bim) {
    acc.x = fmaf(a.x, bre, fmaf(-a.y, bim, acc.x));
    acc.y = fmaf(a.x, bim, fmaf(a.y, bre, acc.y));
}

// ---------------------------------------------------------------------------
// Setup kernel: one block of 256 threads builds T2 (32x32 complex).
// Thread (i = tid>>3, jq = (tid&7)*4) owns 4 columns of row i.
//   H from params  ->  U = expm(iH) (scale & square + Taylor-Horner,
//   double-buffered: 1 barrier per matmul)
//   W = U^T U      ->  mix = (1.1 I - W)^{-1} W  (pivot-free Gauss-Jordan:
//   every leading block of 1.1I - W has sigma_min >= 0.1, pivots safe)
//   T2[i][j] = -kappa_i*kappa_j*(0.5*delta_ij + mix[i][j])
// ---------------------------------------------------------------------------
__global__ __launch_bounds__(256) void setup_kernel(const float* __restrict__ params,
                                                    const float* __restrict__ kappa) {
    __shared__ float2 X[NMODES][NMODES];
    __shared__ float2 B0[NMODES][NMODES];
    __shared__ float2 B1[NMODES][NMODES];
    __shared__ float2 Aug[NMODES][2 * NMODES];
    __shared__ int sh_s;
    __shared__ float sh_scale;

    const int tid = threadIdx.x;
    const int i = tid >> 3;
    const int jq = (tid & 7) << 2;

    // --- build H (4 elements per thread) ---
#pragma unroll
    for (int c = 0; c < 4; ++c) {
        int j = jq + c;
        float2 h;
        if (i == j) {
            float d;
            if (i < 31) {
                d = params[2 * NPAIR + i];
            } else {
                d = 0.0f;
                for (int r = 0; r < 31; ++r) d -= params[2 * NPAIR + r];
            }
            h = make_float2(d, 0.0f);
        } else {
            int a = (i < j) ? i : j;
            int b = (i < j) ? j : i;
            int idx = 31 * a - (a * (a - 1)) / 2 + (b - a - 1);  // row-major triu
            float re = params[idx];
            float im = params[NPAIR + idx];
            h = (i < j) ? make_float2(re, im) : make_float2(re, -im);
        }
        X[i][j] = h;
    }
    __syncthreads();

    // --- inf-norm (lanes 0..31 of wave 0) + scaling exponent ---
    if (tid < 32) {
        float s = 0.0f;
        for (int c = 0; c < NMODES; ++c) {
            float2 v = X[tid][c];
            s += sqrtf(v.x * v.x + v.y * v.y);
        }
        for (int off = 16; off > 0; off >>= 1)
            s = fmaxf(s, __shfl_down(s, off));
        if (tid == 0) {
            int sc_n = 0;
            float sc = 1.0f;
            while (s > 0.25f && sc_n < 40) { s *= 0.5f; sc *= 0.5f; ++sc_n; }
            sh_s = sc_n;
            sh_scale = sc;
        }
    }
    __syncthreads();

    // --- X = (i*H) * 2^{-s}; B0 = I ---
    {
        float sc = sh_scale;
#pragma unroll
        for (int c = 0; c < 4; ++c) {
            int j = jq + c;
            float2 v = X[i][j];
            X[i][j] = make_float2(-v.y * sc, v.x * sc);
            B0[i][j] = make_float2((i == j) ? 1.0f : 0.0f, 0.0f);
        }
    }
    __syncthreads();

    float2 (*cur)[NMODES] = B0;
    float2 (*nxt)[NMODES] = B1;

    // --- Taylor-Horner: for k=N..1: nxt = I + (X*cur)/k  (1 barrier/iter) ---
    for (int k = TAYLOR_N; k >= 1; --k) {
        float2 acc0 = {0, 0}, acc1 = {0, 0}, acc2 = {0, 0}, acc3 = {0, 0};
        for (int kk = 0; kk < NMODES; ++kk) {
            float2 a = X[i][kk];
            float4 b01 = *(const float4*)&cur[kk][jq];
            float4 b23 = *(const float4*)&cur[kk][jq + 2];
            cfma(acc0, a, b01.x, b01.y);
            cfma(acc1, a, b01.z, b01.w);
            cfma(acc2, a, b23.x, b23.y);
            cfma(acc3, a, b23.z, b23.w);
        }
        float invk = 1.0f / (float)k;
        nxt[i][jq + 0] = make_float2(((i == jq + 0) ? 1.0f : 0.0f) + acc0.x * invk, acc0.y * invk);
        nxt[i][jq + 1] = make_float2(((i == jq + 1) ? 1.0f : 0.0f) + acc1.x * invk, acc1.y * invk);
        nxt[i][jq + 2] = make_float2(((i == jq + 2) ? 1.0f : 0.0f) + acc2.x * invk, acc2.y * invk);
        nxt[i][jq + 3] = make_float2(((i == jq + 3) ? 1.0f : 0.0f) + acc3.x * invk, acc3.y * invk);
        __syncthreads();
        float2 (*tmp)[NMODES] = cur; cur = nxt; nxt = tmp;
    }

    // --- squarings: nxt = cur*cur  (1 barrier/iter) ---
    {
        int s = sh_s;
        for (int q = 0; q < s; ++q) {
            float2 acc0 = {0, 0}, acc1 = {0, 0}, acc2 = {0, 0}, acc3 = {0, 0};
            for (int kk = 0; kk < NMODES; ++kk) {
                float2 a = cur[i][kk];
                float4 b01 = *(const float4*)&cur[kk][jq];
                float4 b23 = *(const float4*)&cur[kk][jq + 2];
                cfma(acc0, a, b01.x, b01.y);
                cfma(acc1, a, b01.z, b01.w);
                cfma(acc2, a, b23.x, b23.y);
                cfma(acc3, a, b23.z, b23.w);
            }
            nxt[i][jq + 0] = acc0;
            nxt[i][jq + 1] = acc1;
            nxt[i][jq + 2] = acc2;
            nxt[i][jq + 3] = acc3;
            __syncthreads();
            float2 (*tmp)[NMODES] = cur; cur = nxt; nxt = tmp;
        }
    }

    // --- W = U^T U; write Aug = [1.1I - W | W] directly ---
    {
        float2 acc0 = {0, 0}, acc1 = {0, 0}, acc2 = {0, 0}, acc3 = {0, 0};
        for (int kk = 0; kk < NMODES; ++kk) {
            float2 a = cur[kk][i];
            float4 b01 = *(const float4*)&cur[kk][jq];
            float4 b23 = *(const float4*)&cur[kk][jq + 2];
            cfma(acc0, a, b01.x, b01.y);
            cfma(acc1, a, b01.z, b01.w);
            cfma(acc2, a, b23.x, b23.y);
            cfma(acc3, a, b23.z, b23.w);
        }
        float2 w[4] = {acc0, acc1, acc2, acc3};
#pragma unroll
        for (int c = 0; c < 4; ++c) {
            int j = jq + c;
            Aug[i][j] = make_float2(((i == j) ? 1.1f : 0.0f) - w[c].x, -w[c].y);
            Aug[i][j + NMODES] = w[c];
        }
    }
    __syncthreads();

    // --- pivot-free Gauss-Jordan (2 barriers/iter) ---
    for (int p = 0; p < NMODES; ++p) {
        float2 d = Aug[p][p];
        float2 f = Aug[i][p];
        float4 L01 = *(const float4*)&Aug[p][jq];
        float4 L23 = *(const float4*)&Aug[p][jq + 2];
        float4 R01 = *(const float4*)&Aug[p][jq + NMODES];
        float4 R23 = *(const float4*)&Aug[p][jq + NMODES + 2];
        __syncthreads();  // snapshot complete
        float den = 1.0f / (d.x * d.x + d.y * d.y);
        float2 pr = make_float2(d.x * den, -d.y * den);  // 1/d
        float2 rpL[4] = {{L01.x, L01.y}, {L01.z, L01.w}, {L23.x, L23.y}, {L23.z, L23.w}};
        float2 rpR[4] = {{R01.x, R01.y}, {R01.z, R01.w}, {R23.x, R23.y}, {R23.z, R23.w}};
        if (i == p) {
#pragma unroll
            for (int c = 0; c < 4; ++c) {
                float2 nL = make_float2(rpL[c].x * pr.x - rpL[c].y * pr.y,
                                        rpL[c].x * pr.y + rpL[c].y * pr.x);
                float2 nR = make_float2(rpR[c].x * pr.x - rpR[c].y * pr.y,
                                        rpR[c].x * pr.y + rpR[c].y * pr.x);
                Aug[p][jq + c] = nL;
                Aug[p][jq + c + NMODES] = nR;
            }
        } else {
            float2 g = make_float2(f.x * pr.x - f.y * pr.y, f.x * pr.y + f.y * pr.x);
#pragma unroll
            for (int c = 0; c < 4; ++c) {
                float2 vL = Aug[i][jq + c];
                float2 vR = Aug[i][jq + c + NMODES];
                vL.x -= g.x * rpL[c].x - g.y * rpL[c].y;
                vL.y -= g.x * rpL[c].y + g.y * rpL[c].x;
                vR.x -= g.x * rpR[c].x - g.y * rpR[c].y;
                vR.y -= g.x * rpR[c].y + g.y * rpR[c].x;
                Aug[i][jq + c] = vL;
                Aug[i][jq + c + NMODES] = vR;
            }
        }
        __syncthreads();
    }

    // --- T2 ---
    {
        float ki = fabsf(kappa[i]);
#pragma unroll
        for (int c = 0; c < 4; ++c) {
            int j = jq + c;
            float2 mix = Aug[i][j + NMODES];
            float kk2 = ki * fabsf(kappa[j]);
            g_T2[i * NMODES + j] = make_float2(-kk2 * (((i == j) ? 0.5f : 0.0f) + mix.x),
                                               -kk2 * mix.y);
        }
    }
}

// ---------------------------------------------------------------------------
// Main ODE kernel, split-K x2: block = 64 threads = 1 wave = 1 batch.
// lane = (m = lane>>1, h = lane&1); each lane holds half of T2 row m and
// computes a half dot; halves combine via __shfl_xor(.,1).
// Sync is WSYNC (lgkmcnt-only): no s_barrier, no vmcnt drain of the
// trajectory stores. xbuf writes are unconditional (both h-lanes hold
// bit-identical values; same-address LDS write is a benign one-wins).
// LDS layout padded: slot(k) = k + (k>=16 ? 2 : 0); h=1 reads start byte 144.
// Output: real plane only (out_size == 200*2048*32).
// ---------------------------------------------------------------------------
__device__ __forceinline__ float2 f_eval(const float4* __restrict__ xq,
                                         float2 ym,
                                         const float2* __restrict__ t2h,
                                         float om, float nl2) {
    float2 acc0 = make_float2(0.0f, 0.0f);
    float2 acc1 = make_float2(0.0f, 0.0f);
#pragma unroll
    for (int j = 0; j < 8; ++j) {
        float4 v = xq[j];  // complex x[h*16+2j], x[h*16+2j+1]
        float2 ta = t2h[2 * j];
        float2 tb = t2h[2 * j + 1];
        acc0.x = fmaf(ta.x, v.x, acc0.x);
        acc0.x = fmaf(-ta.y, v.y, acc0.x);
        acc0.y = fmaf(ta.x, v.y, acc0.y);
        acc0.y = fmaf(ta.y, v.x, acc0.y);
        acc1.x = fmaf(tb.x, v.z, acc1.x);
        acc1.x = fmaf(-tb.y, v.w, acc1.x);
        acc1.y = fmaf(tb.x, v.w, acc1.y);
        acc1.y = fmaf(tb.y, v.z, acc1.y);
    }
    float2 acc = make_float2(acc0.x + acc1.x, acc0.y + acc1.y);
    acc.x += __shfl_xor(acc.x, 1);  // combine K-halves; both lanes get full sum
    acc.y += __shfl_xor(acc.y, 1);
    float w = fmaf(nl2, fmaf(ym.x, ym.x, ym.y * ym.y), om);
    return make_float2(acc.x - w * ym.y, acc.y + w * ym.x);
}

__global__ __launch_bounds__(64) void ode_kernel(const float* __restrict__ A0r,
                                                 const float* __restrict__ A0i,
                                                 const float* __restrict__ omega,
                                                 const float* __restrict__ nln,
                                                 float* __restrict__ out,
                                                 long long out_size) {
    const int lane = threadIdx.x;
    const int m = lane >> 1;
    const int h = lane & 1;
    const int b = blockIdx.x;

    // half T2 row: 16 complex = 32 VGPRs
    float2 t2h[16];
#pragma unroll
    for (int j = 0; j < 16; ++j) t2h[j] = g_T2[m * NMODES + h * 16 + j];

    const float om = omega[m];
    const float nl = nln[0];
    const float nl2 = nl * nl;
    const float dt = 1.0f / 199.0f;
    const float hdt = 0.5f * dt;
    const float sdt = dt / 6.0f;

    float2 a;
    if (m < 24) a = make_float2(A0r[b * 24 + m], A0i[b * 24 + m]);
    else        a = make_float2(1.0f, 0.0f);

    __shared__ __align__(16) float2 xbuf[36];  // 32 complex + 2-slot pad at 16
    const int swi = m + ((m >= 16) ? 2 : 0);   // write slot for mode m
    const float4* xq = reinterpret_cast<const float4*>(xbuf) + 9 * h;  // h=1 -> byte 144

    // t = 0 output (real plane only, guarded)
    if (h == 0) {
        long long o = (long long)b * 32 + m;
        if (o < out_size) out[o] = a.x;
    }
    xbuf[swi] = a;
    WSYNC();

    for (int t = 1; t < 200; ++t) {
        float2 k1 = f_eval(xq, a, t2h, om, nl2);
        float2 y2 = make_float2(fmaf(hdt, k1.x, a.x), fmaf(hdt, k1.y, a.y));
        xbuf[swi] = y2;
        WSYNC();

        float2 k2 = f_eval(xq, y2, t2h, om, nl2);
        float2 y3 = make_float2(fmaf(hdt, k2.x, a.x), fmaf(hdt, k2.y, a.y));
        xbuf[swi] = y3;
        WSYNC();

        float2 k3 = f_eval(xq, y3, t2h, om, nl2);
        float2 y4 = make_float2(fmaf(dt, k3.x, a.x), fmaf(dt, k3.y, a.y));
        xbuf[swi] = y4;
        WSYNC();

        float2 k4 = f_eval(xq, y4, t2h, om, nl2);

        a.x = fmaf(sdt, k1.x + 2.0f * k2.x + 2.0f * k3.x + k4.x, a.x);
        a.y = fmaf(sdt, k1.y + 2.0f * k2.y + 2.0f * k3.y + k4.y, a.y);

        xbuf[swi] = a;
        if (h == 0) {
            long long o = (long long)t * 65536 + (long long)b * 32 + m;
            if (o < out_size) out[o] = a.x;
        }
        WSYNC();
    }
}

extern "C" void kernel_launch(void* const* d_in, const int* in_sizes, int n_in,
                              void* d_out, int out_size, void* d_ws, size_t ws_size,
                              hipStream_t stream) {
    const float* A0r = (const float*)d_in[0];
    const float* A0i = (const float*)d_in[1];
    const float* omega = (const float*)d_in[2];
    const float* kappa = (const float*)d_in[3];
    const float* nln = (const float*)d_in[4];
    const float* params = (const float*)d_in[5];

    setup_kernel<<<1, 256, 0, stream>>>(params, kappa);
    ode_kernel<<<2048, 64, 0, stream>>>(A0r, A0i, omega, nln,
                                        (float*)d_out, (long long)out_size);
}